// Round 1
// baseline (381.489 us; speedup 1.0000x reference)
//
#include <hip/hip_runtime.h>

#define BB 64
#define NN 196
#define EE 768
#define HH 16
#define DHH 48
// M = BB*NN = 12544 rows for all projections

typedef short bf16x8 __attribute__((ext_vector_type(8)));
typedef float f32x4 __attribute__((ext_vector_type(4)));
typedef unsigned short u16;
typedef unsigned int u32;

static __device__ __forceinline__ u16 f2bf(float f) {
  union { float f; u32 u; } un; un.f = f;
  u32 u = un.u;
  u32 r = (u + 0x7fffu + ((u >> 16) & 1u)) >> 16;  // round-to-nearest-even
  return (u16)r;
}

// ---------------------------------------------------------------------------
// Positional bias: pos[h][q][k] = softmax_k( Wpos[h]·(dx,dy,dx^2+dy^2) + bpos[h] )
// Exact fp32; tiny (H*N*N = 614656 floats). One block per (h,q) row.
// ---------------------------------------------------------------------------
__global__ __launch_bounds__(64) void pos_kernel(const float* __restrict__ Wpos,
                                                 const float* __restrict__ bpos,
                                                 float* __restrict__ pos) {
  int bid = blockIdx.x;
  int h = bid / NN, q = bid % NN;
  int lane = threadIdx.x;
  float w0 = Wpos[h * 3 + 0], w1 = Wpos[h * 3 + 1], w2 = Wpos[h * 3 + 2];
  float bb = bpos[h];
  int qx = q % 14, qy = q / 14;
  float e[4];
  float mx = -1e30f;
#pragma unroll
  for (int i = 0; i < 4; ++i) {
    int k = lane + 64 * i;
    float val = -1e30f;
    if (k < NN) {
      int kx = k % 14, ky = k / 14;
      float dx = (float)(kx - qx), dy = (float)(ky - qy);
      val = w0 * dx + w1 * dy + w2 * (dx * dx + dy * dy) + bb;
    }
    e[i] = val;
    mx = fmaxf(mx, val);
  }
#pragma unroll
  for (int off = 1; off < 64; off <<= 1) mx = fmaxf(mx, __shfl_xor(mx, off));
  float s = 0.f;
#pragma unroll
  for (int i = 0; i < 4; ++i) {
    int k = lane + 64 * i;
    float p = (k < NN) ? expf(e[i] - mx) : 0.f;
    e[i] = p;
    s += p;
  }
#pragma unroll
  for (int off = 1; off < 64; off <<= 1) s += __shfl_xor(s, off);
  float inv = 1.f / s;
#pragma unroll
  for (int i = 0; i < 4; ++i) {
    int k = lane + 64 * i;
    if (k < NN) pos[(size_t)h * NN * NN + (size_t)q * NN + k] = e[i] * inv;
  }
}

// ---------------------------------------------------------------------------
// GEMM: Y[m][n] = sum_k A[m][k] * W[n][k]  (i.e. A @ W^T), M=12544, N=K=768.
// A is f32 (projections) or bf16 (final, from ctx). Out bf16 or f32(+bias).
// BM=BN=64, BK=32, 256 threads = 4 waves in 2x2, each wave 32x32 via 4 MFMAs.
// ---------------------------------------------------------------------------
template <bool A_BF16, bool OUT_F32>
__global__ __launch_bounds__(256) void gemm_kernel(const void* __restrict__ Aptr,
                                                   const float* __restrict__ W,
                                                   void* __restrict__ Yptr,
                                                   const float* __restrict__ bias) {
  __shared__ u16 As[64 * 40];  // stride 40 shorts (80B): 16B-aligned rows, 2-way banks
  __shared__ u16 Bs[64 * 40];
  int m0 = blockIdx.x * 64, n0 = blockIdx.y * 64;
  int tid = threadIdx.x;
  int lane = tid & 63, wid = tid >> 6;
  int wm = wid >> 1, wn = wid & 1;
  int r16 = lane & 15, g4 = lane >> 4;
  f32x4 acc[2][2];
#pragma unroll
  for (int i = 0; i < 2; ++i)
#pragma unroll
    for (int j = 0; j < 2; ++j) acc[i][j] = (f32x4){0.f, 0.f, 0.f, 0.f};

  for (int k0 = 0; k0 < EE; k0 += 32) {
#pragma unroll
    for (int c = 0; c < 2; ++c) {
      int idx = tid + c * 256;
      int row = idx >> 3, k4 = (idx & 7) << 2;
      short4 sv;
      if (A_BF16) {
        sv = *(const short4*)((const u16*)Aptr + (size_t)(m0 + row) * EE + k0 + k4);
      } else {
        float4 fv = *(const float4*)((const float*)Aptr + (size_t)(m0 + row) * EE + k0 + k4);
        sv.x = (short)f2bf(fv.x);
        sv.y = (short)f2bf(fv.y);
        sv.z = (short)f2bf(fv.z);
        sv.w = (short)f2bf(fv.w);
      }
      *(short4*)&As[row * 40 + k4] = sv;
      float4 wv = *(const float4*)(W + (size_t)(n0 + row) * EE + k0 + k4);
      short4 sw;
      sw.x = (short)f2bf(wv.x);
      sw.y = (short)f2bf(wv.y);
      sw.z = (short)f2bf(wv.z);
      sw.w = (short)f2bf(wv.w);
      *(short4*)&Bs[row * 40 + k4] = sw;
    }
    __syncthreads();
    bf16x8 a0 = *(const bf16x8*)&As[(wm * 32 + r16) * 40 + g4 * 8];
    bf16x8 a1 = *(const bf16x8*)&As[(wm * 32 + 16 + r16) * 40 + g4 * 8];
    bf16x8 b0 = *(const bf16x8*)&Bs[(wn * 32 + r16) * 40 + g4 * 8];
    bf16x8 b1 = *(const bf16x8*)&Bs[(wn * 32 + 16 + r16) * 40 + g4 * 8];
    acc[0][0] = __builtin_amdgcn_mfma_f32_16x16x32_bf16(a0, b0, acc[0][0], 0, 0, 0);
    acc[0][1] = __builtin_amdgcn_mfma_f32_16x16x32_bf16(a0, b1, acc[0][1], 0, 0, 0);
    acc[1][0] = __builtin_amdgcn_mfma_f32_16x16x32_bf16(a1, b0, acc[1][0], 0, 0, 0);
    acc[1][1] = __builtin_amdgcn_mfma_f32_16x16x32_bf16(a1, b1, acc[1][1], 0, 0, 0);
    __syncthreads();
  }
#pragma unroll
  for (int i = 0; i < 2; ++i)
#pragma unroll
    for (int j = 0; j < 2; ++j)
#pragma unroll
      for (int v = 0; v < 4; ++v) {
        int row = m0 + wm * 32 + i * 16 + g4 * 4 + v;
        int col = n0 + wn * 32 + j * 16 + r16;
        float val = acc[i][j][v];
        if (OUT_F32)
          ((float*)Yptr)[(size_t)row * EE + col] = val + bias[col];
        else
          ((u16*)Yptr)[(size_t)row * EE + col] = f2bf(val);
      }
}

// ---------------------------------------------------------------------------
// Fused gated attention. One block per (b,h); 512 threads = 8 waves.
// Q,K row-major bf16 LDS (stride 72), V transposed (48 x 224, stride 232),
// per-wave score buffer (16 x 224, stride 232). Row-tiles of 16 q-rows;
// QK^T and PV via 16x16x32 bf16 MFMA (d padded 48->64, keys padded 196->208/224
// with zeros). Softmax/gating/renorm in fp32. pos read exact from global (L3).
// ---------------------------------------------------------------------------
__global__ __launch_bounds__(512) void attn_kernel(const u16* __restrict__ Qp,
                                                   const u16* __restrict__ Kp,
                                                   const u16* __restrict__ Vp,
                                                   const float* __restrict__ pos,
                                                   const float* __restrict__ gating,
                                                   u16* __restrict__ ctx) {
  __shared__ u16 Qs[208 * 72];
  __shared__ u16 Ks[208 * 72];
  __shared__ u16 Vt[48 * 232];
  __shared__ u16 sc[8][16 * 232];
  int bh = blockIdx.x;
  int b = bh >> 4, h = bh & 15;
  int tid = threadIdx.x;
  {  // zero-fill Q/K/V LDS (padding must be 0, not garbage/NaN)
    u32* z = (u32*)&Qs[0];
    for (int i = tid; i < (208 * 72) / 2; i += 512) z[i] = 0u;
    z = (u32*)&Ks[0];
    for (int i = tid; i < (208 * 72) / 2; i += 512) z[i] = 0u;
    z = (u32*)&Vt[0];
    for (int i = tid; i < (48 * 232) / 2; i += 512) z[i] = 0u;
  }
  __syncthreads();
  const u16* Qb = Qp + (size_t)b * NN * EE + h * DHH;
  const u16* Kb = Kp + (size_t)b * NN * EE + h * DHH;
  const u16* Vb = Vp + (size_t)b * NN * EE + h * DHH;
  for (int c = tid; c < NN * 12; c += 512) {
    int row = c / 12, k4 = (c % 12) * 4;
    short4 v = *(const short4*)(Qb + (size_t)row * EE + k4);
    *(short4*)&Qs[row * 72 + k4] = v;
  }
  for (int c = tid; c < NN * 12; c += 512) {
    int row = c / 12, k4 = (c % 12) * 4;
    short4 v = *(const short4*)(Kb + (size_t)row * EE + k4);
    *(short4*)&Ks[row * 72 + k4] = v;
  }
  for (int c = tid; c < NN * 12; c += 512) {
    int key = c / 12, d4 = (c % 12) * 4;
    short4 v = *(const short4*)(Vb + (size_t)key * EE + d4);
    Vt[(d4 + 0) * 232 + key] = (u16)v.x;
    Vt[(d4 + 1) * 232 + key] = (u16)v.y;
    Vt[(d4 + 2) * 232 + key] = (u16)v.z;
    Vt[(d4 + 3) * 232 + key] = (u16)v.w;
  }
  __syncthreads();

  int wid = tid >> 6, lane = tid & 63;
  int r16 = lane & 15, g4 = lane >> 4;
  float g = 1.f / (1.f + expf(-gating[h]));
  float omg = 1.f - g;
  u16* scw = &sc[wid][0];
  const float scale = 0.14433756729740643f;  // 1/sqrt(48)
  const float* posh = pos + (size_t)h * NN * NN;

  for (int rt = wid; rt < 13; rt += 8) {
    int q0 = rt * 16;
    bf16x8 aQ0 = *(const bf16x8*)&Qs[(q0 + r16) * 72 + g4 * 8];
    bf16x8 aQ1 = *(const bf16x8*)&Qs[(q0 + r16) * 72 + 32 + g4 * 8];
    f32x4 e[13];
#pragma unroll
    for (int ct = 0; ct < 13; ++ct) {
      bf16x8 b0 = *(const bf16x8*)&Ks[(ct * 16 + r16) * 72 + g4 * 8];
      bf16x8 b1 = *(const bf16x8*)&Ks[(ct * 16 + r16) * 72 + 32 + g4 * 8];
      f32x4 t = (f32x4){0.f, 0.f, 0.f, 0.f};
      t = __builtin_amdgcn_mfma_f32_16x16x32_bf16(aQ0, b0, t, 0, 0, 0);
      t = __builtin_amdgcn_mfma_f32_16x16x32_bf16(aQ1, b1, t, 0, 0, 0);
      e[ct] = t;
    }
    // scale + mask padded keys; row max (rows r = 4*g4+v live in 16-lane groups)
    float mx[4] = {-1e30f, -1e30f, -1e30f, -1e30f};
#pragma unroll
    for (int ct = 0; ct < 13; ++ct) {
      int cix = ct * 16 + r16;
      bool valid = cix < NN;
#pragma unroll
      for (int v = 0; v < 4; ++v) {
        float ev = e[ct][v] * scale;
        ev = valid ? ev : -1e30f;
        e[ct][v] = ev;
        mx[v] = fmaxf(mx[v], ev);
      }
    }
#pragma unroll
    for (int v = 0; v < 4; ++v)
#pragma unroll
      for (int off = 1; off < 16; off <<= 1) mx[v] = fmaxf(mx[v], __shfl_xor(mx[v], off));
    float sm[4] = {0.f, 0.f, 0.f, 0.f};
#pragma unroll
    for (int ct = 0; ct < 13; ++ct)
#pragma unroll
      for (int v = 0; v < 4; ++v) {
        float p = __expf(e[ct][v] - mx[v]);
        e[ct][v] = p;
        sm[v] += p;
      }
#pragma unroll
    for (int v = 0; v < 4; ++v)
#pragma unroll
      for (int off = 1; off < 16; off <<= 1) sm[v] += __shfl_xor(sm[v], off);
    float inv[4];
#pragma unroll
    for (int v = 0; v < 4; ++v) inv[v] = 1.f / sm[v];
    // gated combine with exact pos, then renormalize (matches reference's div)
    int qg[4];
#pragma unroll
    for (int v = 0; v < 4; ++v) qg[v] = q0 + g4 * 4 + v;
    float t2[4] = {0.f, 0.f, 0.f, 0.f};
#pragma unroll
    for (int ct = 0; ct < 13; ++ct) {
      int cix = ct * 16 + r16;
      bool valid = cix < NN;
#pragma unroll
      for (int v = 0; v < 4; ++v) {
        float content = e[ct][v] * inv[v];
        float pv = 0.f;
        if (valid && qg[v] < NN) pv = posh[(size_t)qg[v] * NN + cix];
        float s = omg * content + g * pv;
        e[ct][v] = s;
        t2[v] += s;
      }
    }
#pragma unroll
    for (int v = 0; v < 4; ++v)
#pragma unroll
      for (int off = 1; off < 16; off <<= 1) t2[v] += __shfl_xor(t2[v], off);
    float inv2[4];
#pragma unroll
    for (int v = 0; v < 4; ++v) inv2[v] = 1.f / t2[v];
    // write renormalized scores as bf16 (cols 208..223 zeroed for K-padding)
#pragma unroll
    for (int ct = 0; ct < 14; ++ct)
#pragma unroll
      for (int v = 0; v < 4; ++v) {
        float s = (ct < 13) ? e[ct][v] * inv2[v] : 0.f;
        scw[(g4 * 4 + v) * 232 + ct * 16 + r16] = f2bf(s);
      }
    asm volatile("s_waitcnt lgkmcnt(0)" ::: "memory");
    // PV: attn[q][d] = sum_k score[q][k] * V[k][d]
#pragma unroll
    for (int dt = 0; dt < 3; ++dt) {
      f32x4 pv = (f32x4){0.f, 0.f, 0.f, 0.f};
#pragma unroll
      for (int kt = 0; kt < 7; ++kt) {
        bf16x8 aS = *(const bf16x8*)&scw[r16 * 232 + kt * 32 + g4 * 8];
        bf16x8 bV = *(const bf16x8*)&Vt[(dt * 16 + r16) * 232 + kt * 32 + g4 * 8];
        pv = __builtin_amdgcn_mfma_f32_16x16x32_bf16(aS, bV, pv, 0, 0, 0);
      }
#pragma unroll
      for (int v = 0; v < 4; ++v) {
        if (qg[v] < NN)
          ctx[((size_t)b * NN + qg[v]) * EE + h * DHH + dt * 16 + r16] = f2bf(pv[v]);
      }
    }
  }
}

// ---------------------------------------------------------------------------
// Workspace layout (bytes): Qp/Kp/Vp/ctx bf16 [12544*768] = 4 * 19,267,584
// then pos f32 [16*196*196] = 2,458,624.  Total ~79.5 MB (needs ws_size >= that).
// ---------------------------------------------------------------------------
extern "C" void kernel_launch(void* const* d_in, const int* in_sizes, int n_in,
                              void* d_out, int out_size, void* d_ws, size_t ws_size,
                              hipStream_t stream) {
  const float* q = (const float*)d_in[0];
  const float* k = (const float*)d_in[1];
  const float* v = (const float*)d_in[2];
  // d_in[3] = mask: all-true in this problem -> where() is identity; unused.
  const float* Wq = (const float*)d_in[4];
  const float* Wk = (const float*)d_in[5];
  const float* Wv = (const float*)d_in[6];
  const float* Wo = (const float*)d_in[7];
  const float* bo = (const float*)d_in[8];
  const float* Wpos = (const float*)d_in[9];
  const float* bpos = (const float*)d_in[10];
  const float* gating = (const float*)d_in[11];
  float* out = (float*)d_out;

  char* ws = (char*)d_ws;
  const size_t elems = (size_t)BB * NN * EE;  // 9,633,792
  u16* Qp = (u16*)ws;
  u16* Kp = Qp + elems;
  u16* Vp = Kp + elems;
  u16* ctx = Vp + elems;
  float* pos = (float*)(ws + 4 * elems * sizeof(u16));

  hipLaunchKernelGGL(pos_kernel, dim3(HH * NN), dim3(64), 0, stream, Wpos, bpos, pos);

  dim3 ggrid(196, 12), gblk(256);
  hipLaunchKernelGGL((gemm_kernel<false, false>), ggrid, gblk, 0, stream,
                     (const void*)q, Wq, (void*)Qp, (const float*)nullptr);
  hipLaunchKernelGGL((gemm_kernel<false, false>), ggrid, gblk, 0, stream,
                     (const void*)k, Wk, (void*)Kp, (const float*)nullptr);
  hipLaunchKernelGGL((gemm_kernel<false, false>), ggrid, gblk, 0, stream,
                     (const void*)v, Wv, (void*)Vp, (const float*)nullptr);

  hipLaunchKernelGGL(attn_kernel, dim3(BB * HH), dim3(512), 0, stream,
                     Qp, Kp, Vp, pos, gating, ctx);

  hipLaunchKernelGGL((gemm_kernel<true, true>), ggrid, gblk, 0, stream,
                     (const void*)ctx, Wo, (void*)out, bo);
}

// Round 2
// 228.105 us; speedup vs baseline: 1.6724x; 1.6724x over previous
//
#include <hip/hip_runtime.h>
#include <hip/hip_bf16.h>

#define BB 64
#define NN 196
#define EE 768
#define HH 16
#define DHH 48
// M = BB*NN = 12544 rows for all projections

typedef short bf16x8 __attribute__((ext_vector_type(8)));
typedef float f32x4 __attribute__((ext_vector_type(4)));
typedef unsigned short u16;
typedef unsigned short u16x8 __attribute__((ext_vector_type(8)));
typedef unsigned int u32;

static __device__ __forceinline__ u16 f2bf(float f) {
  union { float f; u32 u; } un; un.f = f;
  u32 u = un.u;
  u32 r = (u + 0x7fffu + ((u >> 16) & 1u)) >> 16;  // round-to-nearest-even
  return (u16)r;
}

// hardware RNE f32->bf16 (compiler emits v_cvt_pk_bf16_f32 for pairs)
static __device__ __forceinline__ u16 f2bf_hw(float f) {
  __hip_bfloat16 h = __float2bfloat16(f);
  return __builtin_bit_cast(u16, h);
}

#define GLOAD16(GP, LP)                                                        \
  __builtin_amdgcn_global_load_lds(                                            \
      (const __attribute__((address_space(1))) void*)(GP),                     \
      (__attribute__((address_space(3))) void*)(LP), 16, 0, 0)

// ---------------------------------------------------------------------------
// Positional bias: pos[h][q][k] = softmax_k( Wpos[h]·(dx,dy,dx^2+dy^2) + bpos[h] )
// Exact fp32; tiny (H*N*N = 614656 floats). One block per (h,q) row.
// ---------------------------------------------------------------------------
__global__ __launch_bounds__(64) void pos_kernel(const float* __restrict__ Wpos,
                                                 const float* __restrict__ bpos,
                                                 float* __restrict__ pos) {
  int bid = blockIdx.x;
  int h = bid / NN, q = bid % NN;
  int lane = threadIdx.x;
  float w0 = Wpos[h * 3 + 0], w1 = Wpos[h * 3 + 1], w2 = Wpos[h * 3 + 2];
  float bb = bpos[h];
  int qx = q % 14, qy = q / 14;
  float e[4];
  float mx = -1e30f;
#pragma unroll
  for (int i = 0; i < 4; ++i) {
    int k = lane + 64 * i;
    float val = -1e30f;
    if (k < NN) {
      int kx = k % 14, ky = k / 14;
      float dx = (float)(kx - qx), dy = (float)(ky - qy);
      val = w0 * dx + w1 * dy + w2 * (dx * dx + dy * dy) + bb;
    }
    e[i] = val;
    mx = fmaxf(mx, val);
  }
#pragma unroll
  for (int off = 1; off < 64; off <<= 1) mx = fmaxf(mx, __shfl_xor(mx, off));
  float s = 0.f;
#pragma unroll
  for (int i = 0; i < 4; ++i) {
    int k = lane + 64 * i;
    float p = (k < NN) ? expf(e[i] - mx) : 0.f;
    e[i] = p;
    s += p;
  }
#pragma unroll
  for (int off = 1; off < 64; off <<= 1) s += __shfl_xor(s, off);
  float inv = 1.f / s;
#pragma unroll
  for (int i = 0; i < 4; ++i) {
    int k = lane + 64 * i;
    if (k < NN) pos[(size_t)h * NN * NN + (size_t)q * NN + k] = e[i] * inv;
  }
}

// ---------------------------------------------------------------------------
// Weight conversion: 4 matrices [768][768] f32 -> bf16, concatenated output.
// ---------------------------------------------------------------------------
__global__ __launch_bounds__(256) void cvtw_kernel(const float* __restrict__ W0,
                                                   const float* __restrict__ W1,
                                                   const float* __restrict__ W2,
                                                   const float* __restrict__ W3,
                                                   u16* __restrict__ out) {
  const float* Ws[4] = {W0, W1, W2, W3};
  int mat = blockIdx.y;
  const float* src = Ws[mat];
  int idx = blockIdx.x * 256 + threadIdx.x;  // float4 index; EE*EE/4 = 147456
  float4 f = ((const float4*)src)[idx];
  short4 s;
  s.x = (short)f2bf_hw(f.x);
  s.y = (short)f2bf_hw(f.y);
  s.z = (short)f2bf_hw(f.z);
  s.w = (short)f2bf_hw(f.w);
  *(short4*)(out + (size_t)mat * EE * EE + (size_t)idx * 4) = s;
}

// ---------------------------------------------------------------------------
// m97-structure GEMM body: Y[m][n] = sum_k A[m][k] * W[n][k], K = EE = 768.
// BM=BN=128, BK=32, 256 threads = 4 waves (2x2), each wave 64x64 via 4x4 MFMAs.
// B (bf16 weights) staged with global_load_lds width-16. A either bf16
// (global_load_lds) or f32 (reg-staged + v_cvt_pk_bf16_f32 + ds_write_b128).
// LDS [128][32] bf16 linear: ds_read_b128 fragment pattern is uniformly
// 8 accesses/bank -> conflict-free; gload dst is linear in tid (lane-order ok).
// ---------------------------------------------------------------------------
template <bool A_BF16, bool OUT_F32>
static __device__ __forceinline__ void gemm_body(const void* __restrict__ Aptr,
                                                 const u16* __restrict__ Wb,
                                                 void* __restrict__ Yptr,
                                                 const float* __restrict__ bias,
                                                 int m0, int n0) {
  __shared__ u16 As[128 * 32];
  __shared__ u16 Bs[128 * 32];
  const int tid = threadIdx.x;
  const int lane = tid & 63, wid = tid >> 6;
  const int wm = wid >> 1, wn = wid & 1;
  const int r16 = lane & 15, g4 = lane >> 4;
  f32x4 acc[4][4];
#pragma unroll
  for (int i = 0; i < 4; ++i)
#pragma unroll
    for (int j = 0; j < 4; ++j) acc[i][j] = (f32x4){0.f, 0.f, 0.f, 0.f};

  const int srow = tid >> 2, sseg = tid & 3;  // gload staging: 4 lanes/row
  const u16* Bg = Wb + (size_t)(n0 + srow) * EE + sseg * 8;
  const int arow = tid >> 1, ahalf = tid & 1;  // f32-A staging: 2 lanes/row

  for (int k0 = 0; k0 < EE; k0 += 32) {
    GLOAD16(Bg + k0, &Bs[tid * 8]);
    GLOAD16(Bg + 64 * EE + k0, &Bs[(256 + tid) * 8]);
    if (A_BF16) {
      const u16* Ag = (const u16*)Aptr + (size_t)(m0 + srow) * EE + sseg * 8 + k0;
      GLOAD16(Ag, &As[tid * 8]);
      GLOAD16(Ag + 64 * EE, &As[(256 + tid) * 8]);
    } else {
      const float* Ag = (const float*)Aptr + (size_t)(m0 + arow) * EE + k0 + ahalf * 16;
      float4 f0 = ((const float4*)Ag)[0];
      float4 f1 = ((const float4*)Ag)[1];
      float4 f2 = ((const float4*)Ag)[2];
      float4 f3 = ((const float4*)Ag)[3];
      u16x8 s0, s1;
      s0[0] = f2bf_hw(f0.x); s0[1] = f2bf_hw(f0.y);
      s0[2] = f2bf_hw(f0.z); s0[3] = f2bf_hw(f0.w);
      s0[4] = f2bf_hw(f1.x); s0[5] = f2bf_hw(f1.y);
      s0[6] = f2bf_hw(f1.z); s0[7] = f2bf_hw(f1.w);
      s1[0] = f2bf_hw(f2.x); s1[1] = f2bf_hw(f2.y);
      s1[2] = f2bf_hw(f2.z); s1[3] = f2bf_hw(f2.w);
      s1[4] = f2bf_hw(f3.x); s1[5] = f2bf_hw(f3.y);
      s1[6] = f2bf_hw(f3.z); s1[7] = f2bf_hw(f3.w);
      u16* dst = &As[arow * 32 + ahalf * 16];
      *(u16x8*)dst = s0;
      *(u16x8*)(dst + 8) = s1;
    }
    __syncthreads();
    bf16x8 af[4], bfr[4];
#pragma unroll
    for (int i = 0; i < 4; ++i)
      af[i] = *(const bf16x8*)&As[(wm * 64 + i * 16 + r16) * 32 + g4 * 8];
#pragma unroll
    for (int j = 0; j < 4; ++j)
      bfr[j] = *(const bf16x8*)&Bs[(wn * 64 + j * 16 + r16) * 32 + g4 * 8];
#pragma unroll
    for (int i = 0; i < 4; ++i)
#pragma unroll
      for (int j = 0; j < 4; ++j)
        acc[i][j] = __builtin_amdgcn_mfma_f32_16x16x32_bf16(af[i], bfr[j], acc[i][j], 0, 0, 0);
    __syncthreads();
  }
#pragma unroll
  for (int i = 0; i < 4; ++i) {
    int row = m0 + wm * 64 + i * 16 + g4 * 4;
#pragma unroll
    for (int j = 0; j < 4; ++j) {
      int col = n0 + wn * 64 + j * 16 + r16;
#pragma unroll
      for (int v = 0; v < 4; ++v) {
        float val = acc[i][j][v];
        if (OUT_F32)
          ((float*)Yptr)[(size_t)(row + v) * EE + col] = val + bias[col];
        else
          ((u16*)Yptr)[(size_t)(row + v) * EE + col] = f2bf(val);
      }
    }
  }
}

// QKV projections batched over blockIdx.z (A = f32 activations, out bf16).
__global__ __launch_bounds__(256) void qkv_gemm(const float* __restrict__ q,
                                                const float* __restrict__ k,
                                                const float* __restrict__ v,
                                                const u16* __restrict__ Wqb,
                                                const u16* __restrict__ Wkb,
                                                const u16* __restrict__ Wvb,
                                                u16* __restrict__ Qp,
                                                u16* __restrict__ Kp,
                                                u16* __restrict__ Vp) {
  int z = blockIdx.z;
  const float* A = (z == 0) ? q : (z == 1) ? k : v;
  const u16* W = (z == 0) ? Wqb : (z == 1) ? Wkb : Wvb;
  u16* Y = (z == 0) ? Qp : (z == 1) ? Kp : Vp;
  gemm_body<false, false>(A, W, Y, nullptr, blockIdx.x * 128, blockIdx.y * 128);
}

// Output projection: A = ctx bf16, out f32 + bias.
__global__ __launch_bounds__(256) void out_gemm(const u16* __restrict__ ctx,
                                                const u16* __restrict__ Wob,
                                                float* __restrict__ out,
                                                const float* __restrict__ bo) {
  gemm_body<true, true>(ctx, Wob, out, bo, blockIdx.x * 128, blockIdx.y * 128);
}

// ---------------------------------------------------------------------------
// Fused gated attention. One block per (b,h); 512 threads = 8 waves.
// (unchanged from round 1 — optimize after GEMMs stop dominating)
// ---------------------------------------------------------------------------
__global__ __launch_bounds__(512) void attn_kernel(const u16* __restrict__ Qp,
                                                   const u16* __restrict__ Kp,
                                                   const u16* __restrict__ Vp,
                                                   const float* __restrict__ pos,
                                                   const float* __restrict__ gating,
                                                   u16* __restrict__ ctx) {
  __shared__ u16 Qs[208 * 72];
  __shared__ u16 Ks[208 * 72];
  __shared__ u16 Vt[48 * 232];
  __shared__ u16 sc[8][16 * 232];
  int bh = blockIdx.x;
  int b = bh >> 4, h = bh & 15;
  int tid = threadIdx.x;
  {  // zero-fill Q/K/V LDS (padding must be 0, not garbage/NaN)
    u32* z = (u32*)&Qs[0];
    for (int i = tid; i < (208 * 72) / 2; i += 512) z[i] = 0u;
    z = (u32*)&Ks[0];
    for (int i = tid; i < (208 * 72) / 2; i += 512) z[i] = 0u;
    z = (u32*)&Vt[0];
    for (int i = tid; i < (48 * 232) / 2; i += 512) z[i] = 0u;
  }
  __syncthreads();
  const u16* Qb = Qp + (size_t)b * NN * EE + h * DHH;
  const u16* Kb = Kp + (size_t)b * NN * EE + h * DHH;
  const u16* Vb = Vp + (size_t)b * NN * EE + h * DHH;
  for (int c = tid; c < NN * 12; c += 512) {
    int row = c / 12, k4 = (c % 12) * 4;
    short4 v = *(const short4*)(Qb + (size_t)row * EE + k4);
    *(short4*)&Qs[row * 72 + k4] = v;
  }
  for (int c = tid; c < NN * 12; c += 512) {
    int row = c / 12, k4 = (c % 12) * 4;
    short4 v = *(const short4*)(Kb + (size_t)row * EE + k4);
    *(short4*)&Ks[row * 72 + k4] = v;
  }
  for (int c = tid; c < NN * 12; c += 512) {
    int key = c / 12, d4 = (c % 12) * 4;
    short4 v = *(const short4*)(Vb + (size_t)key * EE + d4);
    Vt[(d4 + 0) * 232 + key] = (u16)v.x;
    Vt[(d4 + 1) * 232 + key] = (u16)v.y;
    Vt[(d4 + 2) * 232 + key] = (u16)v.z;
    Vt[(d4 + 3) * 232 + key] = (u16)v.w;
  }
  __syncthreads();

  int wid = tid >> 6, lane = tid & 63;
  int r16 = lane & 15, g4 = lane >> 4;
  float g = 1.f / (1.f + expf(-gating[h]));
  float omg = 1.f - g;
  u16* scw = &sc[wid][0];
  const float scale = 0.14433756729740643f;  // 1/sqrt(48)
  const float* posh = pos + (size_t)h * NN * NN;

  for (int rt = wid; rt < 13; rt += 8) {
    int q0 = rt * 16;
    bf16x8 aQ0 = *(const bf16x8*)&Qs[(q0 + r16) * 72 + g4 * 8];
    bf16x8 aQ1 = *(const bf16x8*)&Qs[(q0 + r16) * 72 + 32 + g4 * 8];
    f32x4 e[13];
#pragma unroll
    for (int ct = 0; ct < 13; ++ct) {
      bf16x8 b0 = *(const bf16x8*)&Ks[(ct * 16 + r16) * 72 + g4 * 8];
      bf16x8 b1 = *(const bf16x8*)&Ks[(ct * 16 + r16) * 72 + 32 + g4 * 8];
      f32x4 t = (f32x4){0.f, 0.f, 0.f, 0.f};
      t = __builtin_amdgcn_mfma_f32_16x16x32_bf16(aQ0, b0, t, 0, 0, 0);
      t = __builtin_amdgcn_mfma_f32_16x16x32_bf16(aQ1, b1, t, 0, 0, 0);
      e[ct] = t;
    }
    // scale + mask padded keys; row max (rows r = 4*g4+v live in 16-lane groups)
    float mx[4] = {-1e30f, -1e30f, -1e30f, -1e30f};
#pragma unroll
    for (int ct = 0; ct < 13; ++ct) {
      int cix = ct * 16 + r16;
      bool valid = cix < NN;
#pragma unroll
      for (int v = 0; v < 4; ++v) {
        float ev = e[ct][v] * scale;
        ev = valid ? ev : -1e30f;
        e[ct][v] = ev;
        mx[v] = fmaxf(mx[v], ev);
      }
    }
#pragma unroll
    for (int v = 0; v < 4; ++v)
#pragma unroll
      for (int off = 1; off < 16; off <<= 1) mx[v] = fmaxf(mx[v], __shfl_xor(mx[v], off));
    float sm[4] = {0.f, 0.f, 0.f, 0.f};
#pragma unroll
    for (int ct = 0; ct < 13; ++ct)
#pragma unroll
      for (int v = 0; v < 4; ++v) {
        float p = __expf(e[ct][v] - mx[v]);
        e[ct][v] = p;
        sm[v] += p;
      }
#pragma unroll
    for (int v = 0; v < 4; ++v)
#pragma unroll
      for (int off = 1; off < 16; off <<= 1) sm[v] += __shfl_xor(sm[v], off);
    float inv[4];
#pragma unroll
    for (int v = 0; v < 4; ++v) inv[v] = 1.f / sm[v];
    // gated combine with exact pos, then renormalize (matches reference's div)
    int qg[4];
#pragma unroll
    for (int v = 0; v < 4; ++v) qg[v] = q0 + g4 * 4 + v;
    float t2[4] = {0.f, 0.f, 0.f, 0.f};
#pragma unroll
    for (int ct = 0; ct < 13; ++ct) {
      int cix = ct * 16 + r16;
      bool valid = cix < NN;
#pragma unroll
      for (int v = 0; v < 4; ++v) {
        float content = e[ct][v] * inv[v];
        float pv = 0.f;
        if (valid && qg[v] < NN) pv = posh[(size_t)qg[v] * NN + cix];
        float s = omg * content + g * pv;
        e[ct][v] = s;
        t2[v] += s;
      }
    }
#pragma unroll
    for (int v = 0; v < 4; ++v)
#pragma unroll
      for (int off = 1; off < 16; off <<= 1) t2[v] += __shfl_xor(t2[v], off);
    float inv2[4];
#pragma unroll
    for (int v = 0; v < 4; ++v) inv2[v] = 1.f / t2[v];
    // write renormalized scores as bf16 (cols 208..223 zeroed for K-padding)
#pragma unroll
    for (int ct = 0; ct < 14; ++ct)
#pragma unroll
      for (int v = 0; v < 4; ++v) {
        float s = (ct < 13) ? e[ct][v] * inv2[v] : 0.f;
        scw[(g4 * 4 + v) * 232 + ct * 16 + r16] = f2bf(s);
      }
    asm volatile("s_waitcnt lgkmcnt(0)" ::: "memory");
    // PV: attn[q][d] = sum_k score[q][k] * V[k][d]
#pragma unroll
    for (int dt = 0; dt < 3; ++dt) {
      f32x4 pv = (f32x4){0.f, 0.f, 0.f, 0.f};
#pragma unroll
      for (int kt = 0; kt < 7; ++kt) {
        bf16x8 aS = *(const bf16x8*)&scw[r16 * 232 + kt * 32 + g4 * 8];
        bf16x8 bV = *(const bf16x8*)&Vt[(dt * 16 + r16) * 232 + kt * 32 + g4 * 8];
        pv = __builtin_amdgcn_mfma_f32_16x16x32_bf16(aS, bV, pv, 0, 0, 0);
      }
#pragma unroll
      for (int v = 0; v < 4; ++v) {
        if (qg[v] < NN)
          ctx[((size_t)b * NN + qg[v]) * EE + h * DHH + dt * 16 + r16] = f2bf(pv[v]);
      }
    }
  }
}

// ---------------------------------------------------------------------------
// Workspace layout (bytes):
//   Qp/Kp/Vp/ctx bf16 [12544*768]  = 4 * 19,267,584 = 77,070,336
//   pos f32 [16*196*196]           = 2,458,624
//   Wqb/Wkb/Wvb/Wob bf16 [768*768] = 4 * 1,179,648 = 4,718,592
//   total ~84.3 MB
// ---------------------------------------------------------------------------
extern "C" void kernel_launch(void* const* d_in, const int* in_sizes, int n_in,
                              void* d_out, int out_size, void* d_ws, size_t ws_size,
                              hipStream_t stream) {
  const float* q = (const float*)d_in[0];
  const float* k = (const float*)d_in[1];
  const float* v = (const float*)d_in[2];
  // d_in[3] = mask: all-true in this problem -> where() is identity; unused.
  const float* Wq = (const float*)d_in[4];
  const float* Wk = (const float*)d_in[5];
  const float* Wv = (const float*)d_in[6];
  const float* Wo = (const float*)d_in[7];
  const float* bo = (const float*)d_in[8];
  const float* Wpos = (const float*)d_in[9];
  const float* bpos = (const float*)d_in[10];
  const float* gating = (const float*)d_in[11];
  float* out = (float*)d_out;

  char* ws = (char*)d_ws;
  const size_t elems = (size_t)BB * NN * EE;  // 9,633,792
  u16* Qp = (u16*)ws;
  u16* Kp = Qp + elems;
  u16* Vp = Kp + elems;
  u16* ctx = Vp + elems;
  float* pos = (float*)(ws + 4 * elems * sizeof(u16));
  u16* Wqb = (u16*)(ws + 4 * elems * sizeof(u16) + (size_t)HH * NN * NN * sizeof(float));
  u16* Wkb = Wqb + (size_t)EE * EE;
  u16* Wvb = Wkb + (size_t)EE * EE;
  u16* Wob = Wvb + (size_t)EE * EE;

  hipLaunchKernelGGL(pos_kernel, dim3(HH * NN), dim3(64), 0, stream, Wpos, bpos, pos);
  hipLaunchKernelGGL(cvtw_kernel, dim3(EE * EE / 4 / 256, 4), dim3(256), 0, stream,
                     Wq, Wk, Wv, Wo, Wqb);

  hipLaunchKernelGGL(qkv_gemm, dim3(98, 6, 3), dim3(256), 0, stream,
                     q, k, v, Wqb, Wkb, Wvb, Qp, Kp, Vp);

  hipLaunchKernelGGL(attn_kernel, dim3(BB * HH), dim3(512), 0, stream,
                     Qp, Kp, Vp, pos, gating, ctx);

  hipLaunchKernelGGL(out_gemm, dim3(98, 6), dim3(256), 0, stream,
                     ctx, Wob, out, bo);
}

// Round 3
// 199.775 us; speedup vs baseline: 1.9096x; 1.1418x over previous
//
#include <hip/hip_runtime.h>
#include <hip/hip_bf16.h>

#define BB 64
#define NN 196
#define EE 768
#define HH 16
#define DHH 48
// M = BB*NN = 12544 rows for all projections

typedef short bf16x8 __attribute__((ext_vector_type(8)));
typedef float f32x4 __attribute__((ext_vector_type(4)));
typedef unsigned short u16;
typedef unsigned short u16x8 __attribute__((ext_vector_type(8)));
typedef unsigned int u32;

static __device__ __forceinline__ u16 f2bf(float f) {
  union { float f; u32 u; } un; un.f = f;
  u32 u = un.u;
  u32 r = (u + 0x7fffu + ((u >> 16) & 1u)) >> 16;  // round-to-nearest-even
  return (u16)r;
}

// hardware RNE f32->bf16 (compiler emits v_cvt_pk_bf16_f32 for pairs)
static __device__ __forceinline__ u16 f2bf_hw(float f) {
  __hip_bfloat16 h = __float2bfloat16(f);
  return __builtin_bit_cast(u16, h);
}

#define GLOAD16(GP, LP)                                                        \
  __builtin_amdgcn_global_load_lds(                                            \
      (const __attribute__((address_space(1))) void*)(GP),                     \
      (__attribute__((address_space(3))) void*)(LP), 16, 0, 0)

// Bijective XCD-chunked blockIdx swizzle (m204 variant): each of the 8 XCDs
// gets a contiguous chunk of logical block ids -> neighbor tiles share L2.
static __device__ __forceinline__ int xcd_swz(int bid, int nwg) {
  int q = nwg >> 3, r = nwg & 7;
  int xcd = bid & 7, i = bid >> 3;
  return (xcd < r ? xcd * (q + 1) : r * (q + 1) + (xcd - r) * q) + i;
}

// ---------------------------------------------------------------------------
// Positional bias: pos[h][q][k] = softmax_k( Wpos[h]·(dx,dy,dx^2+dy^2) + bpos[h] )
// ---------------------------------------------------------------------------
__global__ __launch_bounds__(64) void pos_kernel(const float* __restrict__ Wpos,
                                                 const float* __restrict__ bpos,
                                                 float* __restrict__ pos) {
  int bid = blockIdx.x;
  int h = bid / NN, q = bid % NN;
  int lane = threadIdx.x;
  float w0 = Wpos[h * 3 + 0], w1 = Wpos[h * 3 + 1], w2 = Wpos[h * 3 + 2];
  float bb = bpos[h];
  int qx = q % 14, qy = q / 14;
  float e[4];
  float mx = -1e30f;
#pragma unroll
  for (int i = 0; i < 4; ++i) {
    int k = lane + 64 * i;
    float val = -1e30f;
    if (k < NN) {
      int kx = k % 14, ky = k / 14;
      float dx = (float)(kx - qx), dy = (float)(ky - qy);
      val = w0 * dx + w1 * dy + w2 * (dx * dx + dy * dy) + bb;
    }
    e[i] = val;
    mx = fmaxf(mx, val);
  }
#pragma unroll
  for (int off = 1; off < 64; off <<= 1) mx = fmaxf(mx, __shfl_xor(mx, off));
  float s = 0.f;
#pragma unroll
  for (int i = 0; i < 4; ++i) {
    int k = lane + 64 * i;
    float p = (k < NN) ? expf(e[i] - mx) : 0.f;
    e[i] = p;
    s += p;
  }
#pragma unroll
  for (int off = 1; off < 64; off <<= 1) s += __shfl_xor(s, off);
  float inv = 1.f / s;
#pragma unroll
  for (int i = 0; i < 4; ++i) {
    int k = lane + 64 * i;
    if (k < NN) pos[(size_t)h * NN * NN + (size_t)q * NN + k] = e[i] * inv;
  }
}

// ---------------------------------------------------------------------------
// Weight conversion: 4 matrices [768][768] f32 -> bf16, concatenated output.
// ---------------------------------------------------------------------------
__global__ __launch_bounds__(256) void cvtw_kernel(const float* __restrict__ W0,
                                                   const float* __restrict__ W1,
                                                   const float* __restrict__ W2,
                                                   const float* __restrict__ W3,
                                                   u16* __restrict__ out) {
  const float* Ws[4] = {W0, W1, W2, W3};
  int mat = blockIdx.y;
  const float* src = Ws[mat];
  int idx = blockIdx.x * 256 + threadIdx.x;  // float4 index; EE*EE/4 = 147456
  float4 f = ((const float4*)src)[idx];
  short4 s;
  s.x = (short)f2bf_hw(f.x);
  s.y = (short)f2bf_hw(f.y);
  s.z = (short)f2bf_hw(f.z);
  s.w = (short)f2bf_hw(f.w);
  *(short4*)(out + (size_t)mat * EE * EE + (size_t)idx * 4) = s;
}

// ---------------------------------------------------------------------------
// m97-structure GEMM body: Y[m][n] = sum_k A[m][k] * W[n][k], K = EE = 768.
// BM=BN=128, BK=32, 256 threads = 4 waves (2x2), each wave 64x64 via 4x4 MFMAs.
// B (bf16 weights) staged with global_load_lds width-16 (linear dst).
// A either bf16 (global_load_lds) or f32: reg-stage 32B/lane from the global
// address matching LDS slot idx*16B, cvt_pk to bf16, ONE linear ds_write_b128
// per slot -> conflict-free (fixes R2's 16-way ds_write conflict).
// ---------------------------------------------------------------------------
template <bool A_BF16, bool OUT_F32>
static __device__ __forceinline__ void gemm_body(const void* __restrict__ Aptr,
                                                 const u16* __restrict__ Wb,
                                                 void* __restrict__ Yptr,
                                                 const float* __restrict__ bias,
                                                 int m0, int n0) {
  __shared__ u16 As[128 * 32];
  __shared__ u16 Bs[128 * 32];
  const int tid = threadIdx.x;
  const int lane = tid & 63, wid = tid >> 6;
  const int wm = wid >> 1, wn = wid & 1;
  const int r16 = lane & 15, g4 = lane >> 4;
  f32x4 acc[4][4];
#pragma unroll
  for (int i = 0; i < 4; ++i)
#pragma unroll
    for (int j = 0; j < 4; ++j) acc[i][j] = (f32x4){0.f, 0.f, 0.f, 0.f};

  const int srow = tid >> 2, sseg = tid & 3;  // LDS slot tid*16B <-> (row,seg)
  const u16* Bg = Wb + (size_t)(n0 + srow) * EE + sseg * 8;

  for (int k0 = 0; k0 < EE; k0 += 32) {
    GLOAD16(Bg + k0, &Bs[tid * 8]);
    GLOAD16(Bg + 64 * EE + k0, &Bs[(256 + tid) * 8]);
    if (A_BF16) {
      const u16* Ag = (const u16*)Aptr + (size_t)(m0 + srow) * EE + sseg * 8 + k0;
      GLOAD16(Ag, &As[tid * 8]);
      GLOAD16(Ag + 64 * EE, &As[(256 + tid) * 8]);
    } else {
#pragma unroll
      for (int c = 0; c < 2; ++c) {
        int idx = c * 256 + tid;
        const float* Ag =
            (const float*)Aptr + (size_t)(m0 + (idx >> 2)) * EE + k0 + (idx & 3) * 8;
        float4 f0 = ((const float4*)Ag)[0];
        float4 f1 = ((const float4*)Ag)[1];
        u16x8 s0;
        s0[0] = f2bf_hw(f0.x); s0[1] = f2bf_hw(f0.y);
        s0[2] = f2bf_hw(f0.z); s0[3] = f2bf_hw(f0.w);
        s0[4] = f2bf_hw(f1.x); s0[5] = f2bf_hw(f1.y);
        s0[6] = f2bf_hw(f1.z); s0[7] = f2bf_hw(f1.w);
        *(u16x8*)&As[idx * 8] = s0;  // linear 16B/lane -> conflict-free
      }
    }
    __syncthreads();
    bf16x8 af[4], bfr[4];
#pragma unroll
    for (int i = 0; i < 4; ++i)
      af[i] = *(const bf16x8*)&As[(wm * 64 + i * 16 + r16) * 32 + g4 * 8];
#pragma unroll
    for (int j = 0; j < 4; ++j)
      bfr[j] = *(const bf16x8*)&Bs[(wn * 64 + j * 16 + r16) * 32 + g4 * 8];
#pragma unroll
    for (int i = 0; i < 4; ++i)
#pragma unroll
      for (int j = 0; j < 4; ++j)
        acc[i][j] = __builtin_amdgcn_mfma_f32_16x16x32_bf16(af[i], bfr[j], acc[i][j], 0, 0, 0);
    __syncthreads();
  }
#pragma unroll
  for (int i = 0; i < 4; ++i) {
    int row = m0 + wm * 64 + i * 16 + g4 * 4;
#pragma unroll
    for (int j = 0; j < 4; ++j) {
      int col = n0 + wn * 64 + j * 16 + r16;
#pragma unroll
      for (int v = 0; v < 4; ++v) {
        float val = acc[i][j][v];
        if (OUT_F32)
          ((float*)Yptr)[(size_t)(row + v) * EE + col] = val + bias[col];
        else
          ((u16*)Yptr)[(size_t)(row + v) * EE + col] = f2bf(val);
      }
    }
  }
}

// QKV projections: 1-D grid of 1764 = 3z * 98m * 6n, XCD-swizzled, n fastest
// so the 6 n-tiles sharing an A panel run adjacently on the same XCD's L2.
__global__ __launch_bounds__(256) void qkv_gemm(const float* __restrict__ q,
                                                const float* __restrict__ k,
                                                const float* __restrict__ v,
                                                const u16* __restrict__ Wqb,
                                                const u16* __restrict__ Wkb,
                                                const u16* __restrict__ Wvb,
                                                u16* __restrict__ Qp,
                                                u16* __restrict__ Kp,
                                                u16* __restrict__ Vp) {
  int sid = xcd_swz(blockIdx.x, 3 * 98 * 6);
  int z = sid / 588, rem = sid % 588;
  int m0 = (rem / 6) * 128, n0 = (rem % 6) * 128;
  const float* A = (z == 0) ? q : (z == 1) ? k : v;
  const u16* W = (z == 0) ? Wqb : (z == 1) ? Wkb : Wvb;
  u16* Y = (z == 0) ? Qp : (z == 1) ? Kp : Vp;
  gemm_body<false, false>(A, W, Y, nullptr, m0, n0);
}

// Output projection: A = ctx bf16, out f32 + bias. 588 blocks, swizzled.
__global__ __launch_bounds__(256) void out_gemm(const u16* __restrict__ ctx,
                                                const u16* __restrict__ Wob,
                                                float* __restrict__ out,
                                                const float* __restrict__ bo) {
  int sid = xcd_swz(blockIdx.x, 98 * 6);
  int m0 = (sid / 6) * 128, n0 = (sid % 6) * 128;
  gemm_body<true, true>(ctx, Wob, out, bo, m0, n0);
}

// ---------------------------------------------------------------------------
// Fused gated attention. One block per (b,h); 512 threads = 8 waves.
// (unchanged — waiting for its counters before touching it)
// ---------------------------------------------------------------------------
__global__ __launch_bounds__(512) void attn_kernel(const u16* __restrict__ Qp,
                                                   const u16* __restrict__ Kp,
                                                   const u16* __restrict__ Vp,
                                                   const float* __restrict__ pos,
                                                   const float* __restrict__ gating,
                                                   u16* __restrict__ ctx) {
  __shared__ u16 Qs[208 * 72];
  __shared__ u16 Ks[208 * 72];
  __shared__ u16 Vt[48 * 232];
  __shared__ u16 sc[8][16 * 232];
  int bh = blockIdx.x;
  int b = bh >> 4, h = bh & 15;
  int tid = threadIdx.x;
  {  // zero-fill Q/K/V LDS (padding must be 0, not garbage/NaN)
    u32* z = (u32*)&Qs[0];
    for (int i = tid; i < (208 * 72) / 2; i += 512) z[i] = 0u;
    z = (u32*)&Ks[0];
    for (int i = tid; i < (208 * 72) / 2; i += 512) z[i] = 0u;
    z = (u32*)&Vt[0];
    for (int i = tid; i < (48 * 232) / 2; i += 512) z[i] = 0u;
  }
  __syncthreads();
  const u16* Qb = Qp + (size_t)b * NN * EE + h * DHH;
  const u16* Kb = Kp + (size_t)b * NN * EE + h * DHH;
  const u16* Vb = Vp + (size_t)b * NN * EE + h * DHH;
  for (int c = tid; c < NN * 12; c += 512) {
    int row = c / 12, k4 = (c % 12) * 4;
    short4 v = *(const short4*)(Qb + (size_t)row * EE + k4);
    *(short4*)&Qs[row * 72 + k4] = v;
  }
  for (int c = tid; c < NN * 12; c += 512) {
    int row = c / 12, k4 = (c % 12) * 4;
    short4 v = *(const short4*)(Kb + (size_t)row * EE + k4);
    *(short4*)&Ks[row * 72 + k4] = v;
  }
  for (int c = tid; c < NN * 12; c += 512) {
    int key = c / 12, d4 = (c % 12) * 4;
    short4 v = *(const short4*)(Vb + (size_t)key * EE + d4);
    Vt[(d4 + 0) * 232 + key] = (u16)v.x;
    Vt[(d4 + 1) * 232 + key] = (u16)v.y;
    Vt[(d4 + 2) * 232 + key] = (u16)v.z;
    Vt[(d4 + 3) * 232 + key] = (u16)v.w;
  }
  __syncthreads();

  int wid = tid >> 6, lane = tid & 63;
  int r16 = lane & 15, g4 = lane >> 4;
  float g = 1.f / (1.f + expf(-gating[h]));
  float omg = 1.f - g;
  u16* scw = &sc[wid][0];
  const float scale = 0.14433756729740643f;  // 1/sqrt(48)
  const float* posh = pos + (size_t)h * NN * NN;

  for (int rt = wid; rt < 13; rt += 8) {
    int q0 = rt * 16;
    bf16x8 aQ0 = *(const bf16x8*)&Qs[(q0 + r16) * 72 + g4 * 8];
    bf16x8 aQ1 = *(const bf16x8*)&Qs[(q0 + r16) * 72 + 32 + g4 * 8];
    f32x4 e[13];
#pragma unroll
    for (int ct = 0; ct < 13; ++ct) {
      bf16x8 b0 = *(const bf16x8*)&Ks[(ct * 16 + r16) * 72 + g4 * 8];
      bf16x8 b1 = *(const bf16x8*)&Ks[(ct * 16 + r16) * 72 + 32 + g4 * 8];
      f32x4 t = (f32x4){0.f, 0.f, 0.f, 0.f};
      t = __builtin_amdgcn_mfma_f32_16x16x32_bf16(aQ0, b0, t, 0, 0, 0);
      t = __builtin_amdgcn_mfma_f32_16x16x32_bf16(aQ1, b1, t, 0, 0, 0);
      e[ct] = t;
    }
    // scale + mask padded keys; row max (rows r = 4*g4+v live in 16-lane groups)
    float mx[4] = {-1e30f, -1e30f, -1e30f, -1e30f};
#pragma unroll
    for (int ct = 0; ct < 13; ++ct) {
      int cix = ct * 16 + r16;
      bool valid = cix < NN;
#pragma unroll
      for (int v = 0; v < 4; ++v) {
        float ev = e[ct][v] * scale;
        ev = valid ? ev : -1e30f;
        e[ct][v] = ev;
        mx[v] = fmaxf(mx[v], ev);
      }
    }
#pragma unroll
    for (int v = 0; v < 4; ++v)
#pragma unroll
      for (int off = 1; off < 16; off <<= 1) mx[v] = fmaxf(mx[v], __shfl_xor(mx[v], off));
    float sm[4] = {0.f, 0.f, 0.f, 0.f};
#pragma unroll
    for (int ct = 0; ct < 13; ++ct)
#pragma unroll
      for (int v = 0; v < 4; ++v) {
        float p = __expf(e[ct][v] - mx[v]);
        e[ct][v] = p;
        sm[v] += p;
      }
#pragma unroll
    for (int v = 0; v < 4; ++v)
#pragma unroll
      for (int off = 1; off < 16; off <<= 1) sm[v] += __shfl_xor(sm[v], off);
    float inv[4];
#pragma unroll
    for (int v = 0; v < 4; ++v) inv[v] = 1.f / sm[v];
    // gated combine with exact pos, then renormalize (matches reference's div)
    int qg[4];
#pragma unroll
    for (int v = 0; v < 4; ++v) qg[v] = q0 + g4 * 4 + v;
    float t2[4] = {0.f, 0.f, 0.f, 0.f};
#pragma unroll
    for (int ct = 0; ct < 13; ++ct) {
      int cix = ct * 16 + r16;
      bool valid = cix < NN;
#pragma unroll
      for (int v = 0; v < 4; ++v) {
        float content = e[ct][v] * inv[v];
        float pv = 0.f;
        if (valid && qg[v] < NN) pv = posh[(size_t)qg[v] * NN + cix];
        float s = omg * content + g * pv;
        e[ct][v] = s;
        t2[v] += s;
      }
    }
#pragma unroll
    for (int v = 0; v < 4; ++v)
#pragma unroll
      for (int off = 1; off < 16; off <<= 1) t2[v] += __shfl_xor(t2[v], off);
    float inv2[4];
#pragma unroll
    for (int v = 0; v < 4; ++v) inv2[v] = 1.f / t2[v];
    // write renormalized scores as bf16 (cols 208..223 zeroed for K-padding)
#pragma unroll
    for (int ct = 0; ct < 14; ++ct)
#pragma unroll
      for (int v = 0; v < 4; ++v) {
        float s = (ct < 13) ? e[ct][v] * inv2[v] : 0.f;
        scw[(g4 * 4 + v) * 232 + ct * 16 + r16] = f2bf(s);
      }
    asm volatile("s_waitcnt lgkmcnt(0)" ::: "memory");
    // PV: attn[q][d] = sum_k score[q][k] * V[k][d]
#pragma unroll
    for (int dt = 0; dt < 3; ++dt) {
      f32x4 pv = (f32x4){0.f, 0.f, 0.f, 0.f};
#pragma unroll
      for (int kt = 0; kt < 7; ++kt) {
        bf16x8 aS = *(const bf16x8*)&scw[r16 * 232 + kt * 32 + g4 * 8];
        bf16x8 bV = *(const bf16x8*)&Vt[(dt * 16 + r16) * 232 + kt * 32 + g4 * 8];
        pv = __builtin_amdgcn_mfma_f32_16x16x32_bf16(aS, bV, pv, 0, 0, 0);
      }
#pragma unroll
      for (int v = 0; v < 4; ++v) {
        if (qg[v] < NN)
          ctx[((size_t)b * NN + qg[v]) * EE + h * DHH + dt * 16 + r16] = f2bf(pv[v]);
      }
    }
  }
}

// ---------------------------------------------------------------------------
// Workspace layout (bytes):
//   Qp/Kp/Vp/ctx bf16 [12544*768]  = 4 * 19,267,584 = 77,070,336
//   pos f32 [16*196*196]           = 2,458,624
//   Wqb/Wkb/Wvb/Wob bf16 [768*768] = 4 * 1,179,648 = 4,718,592
//   total ~84.3 MB
// ---------------------------------------------------------------------------
extern "C" void kernel_launch(void* const* d_in, const int* in_sizes, int n_in,
                              void* d_out, int out_size, void* d_ws, size_t ws_size,
                              hipStream_t stream) {
  const float* q = (const float*)d_in[0];
  const float* k = (const float*)d_in[1];
  const float* v = (const float*)d_in[2];
  // d_in[3] = mask: all-true in this problem -> where() is identity; unused.
  const float* Wq = (const float*)d_in[4];
  const float* Wk = (const float*)d_in[5];
  const float* Wv = (const float*)d_in[6];
  const float* Wo = (const float*)d_in[7];
  const float* bo = (const float*)d_in[8];
  const float* Wpos = (const float*)d_in[9];
  const float* bpos = (const float*)d_in[10];
  const float* gating = (const float*)d_in[11];
  float* out = (float*)d_out;

  char* ws = (char*)d_ws;
  const size_t elems = (size_t)BB * NN * EE;  // 9,633,792
  u16* Qp = (u16*)ws;
  u16* Kp = Qp + elems;
  u16* Vp = Kp + elems;
  u16* ctx = Vp + elems;
  float* pos = (float*)(ws + 4 * elems * sizeof(u16));
  u16* Wqb = (u16*)(ws + 4 * elems * sizeof(u16) + (size_t)HH * NN * NN * sizeof(float));
  u16* Wkb = Wqb + (size_t)EE * EE;
  u16* Wvb = Wkb + (size_t)EE * EE;
  u16* Wob = Wvb + (size_t)EE * EE;

  hipLaunchKernelGGL(pos_kernel, dim3(HH * NN), dim3(64), 0, stream, Wpos, bpos, pos);
  hipLaunchKernelGGL(cvtw_kernel, dim3(EE * EE / 4 / 256, 4), dim3(256), 0, stream,
                     Wq, Wk, Wv, Wo, Wqb);

  hipLaunchKernelGGL(qkv_gemm, dim3(3 * 98 * 6), dim3(256), 0, stream,
                     q, k, v, Wqb, Wkb, Wvb, Qp, Kp, Vp);

  hipLaunchKernelGGL(attn_kernel, dim3(BB * HH), dim3(512), 0, stream,
                     Qp, Kp, Vp, pos, gating, ctx);

  hipLaunchKernelGGL(out_gemm, dim3(98 * 6), dim3(256), 0, stream,
                     ctx, Wob, out, bo);
}